// Round 11
// baseline (202.264 us; speedup 1.0000x reference)
//
#include <hip/hip_runtime.h>
#include <math.h>

#define EPS 1e-5f
#define KEXP 4.8089834696298780f  // log2(e)/0.3 : exp(x/h) == exp2(x*KEXP)

typedef short short8  __attribute__((ext_vector_type(8)));
typedef float f32x4   __attribute__((ext_vector_type(4)));
typedef float f32x16  __attribute__((ext_vector_type(16)));

static __device__ __forceinline__ unsigned short f2bf(float x) {
  unsigned int b = __float_as_uint(x);
  b += 0x7FFFu + ((b >> 16) & 1u);  // RNE
  return (unsigned short)(b >> 16);
}
static __device__ __forceinline__ unsigned encf(float f) {
  unsigned b = __float_as_uint(f);
  return (b & 0x80000000u) ? ~b : (b | 0x80000000u);
}
static __device__ __forceinline__ float decf(unsigned u) {
  return (u & 0x80000000u) ? __uint_as_float(u & 0x7FFFFFFFu)
                           : __uint_as_float(~u);
}

// async global->LDS, 16B per lane (wave-uniform base + lane*16 semantics)
static __device__ __forceinline__ void dma16(const uint4* g, uint4* l) {
  __builtin_amdgcn_global_load_lds(
      (const __attribute__((address_space(1))) unsigned int*)g,
      (__attribute__((address_space(3))) unsigned int*)l, 16, 0, 0);
}

// ---------------------------------------------------------------------------
// prep bodies: normalize column j over C, cast bf16, write MFMA-blocked.
// JT=16 (16x16x32 frags):  (j,c) -> u4[ ((j>>4)*(C/32) + (c>>5))*64
//                                       + ((c>>3)&3)*16 + (j&15) ]
// JT=32 (32x32x16 frags):  (j,c) -> u4[ ((j>>5)*(C/16) + (c>>4))*64
//                                       + 32*((c>>3)&1) + (j&31) ]
// In both, one uint4 = 8 consecutive-c bf16 = one lane's fragment slice;
// a fragment is chunk_base + lane*16B (dma16/ds_read_b128-compatible).
// ---------------------------------------------------------------------------
template <int C, int HW, int JT>
__device__ __forceinline__ void prep_body(const float* __restrict__ f,
                                          uint4* __restrict__ out, int idx) {
  int b = idx / HW, j = idx - b * HW;
  const float* p = f + (size_t)b * C * HW + j;
  float ssq = 0.f;
  for (int c = 0; c < C; ++c) { float v = p[(size_t)c * HW]; ssq = fmaf(v, v, ssq); }
  float inv = 1.0f / (sqrtf(ssq) + EPS);
  uint4* ob;
  if (JT == 16) {
    constexpr int KC = C / 32;
    ob = out + (size_t)b * (HW / 16) * KC * 64 + (size_t)(j >> 4) * KC * 64 + (j & 15);
  } else {
    constexpr int KC = C / 16;
    ob = out + (size_t)b * (HW / 32) * KC * 64 + (size_t)(j >> 5) * KC * 64 + (j & 31);
  }
  for (int c0 = 0; c0 < C; c0 += 8) {
    unsigned w[4];
#pragma unroll
    for (int h = 0; h < 4; ++h) {
      float v0 = p[(size_t)(c0 + 2 * h) * HW] * inv;
      float v1 = p[(size_t)(c0 + 2 * h + 1) * HW] * inv;
      w[h] = (unsigned)f2bf(v0) | ((unsigned)f2bf(v1) << 16);
    }
    size_t off = (JT == 16) ? ((size_t)(c0 >> 5) * 64 + ((c0 >> 3) & 3) * 16)
                            : ((size_t)(c0 >> 4) * 64 + ((c0 >> 3) & 1) * 32);
    ob[off] = make_uint4(w[0], w[1], w[2], w[3]);
  }
}

// prep + init of dE (0xFF), S (0), out (0) in one launch
__global__ __launch_bounds__(256) void prep_all(
    const float* __restrict__ fx1, uint4* __restrict__ fx1B,
    const float* __restrict__ fy1, uint4* __restrict__ fy1B,
    const float* __restrict__ fx2, uint4* __restrict__ fx2B,
    const float* __restrict__ fy2, uint4* __restrict__ fy2B,
    unsigned* __restrict__ dE, float* __restrict__ S, float* __restrict__ out) {
  int bid = blockIdx.x;
  if (bid < 128)       prep_body<128, 4096, 32>(fx1, fx1B, bid * 256 + threadIdx.x);
  else if (bid < 256)  prep_body<128, 4096, 32>(fy1, fy1B, (bid - 128) * 256 + threadIdx.x);
  else if (bid < 288)  prep_body<256, 1024, 16>(fx2, fx2B, (bid - 256) * 256 + threadIdx.x);
  else if (bid < 320)  prep_body<256, 1024, 16>(fy2, fy2B, (bid - 288) * 256 + threadIdx.x);
  else {
    int t = (bid - 320) * 256 + threadIdx.x;  // 16 blocks -> 4096 threads
    for (int k = t; k < 8 * (4096 + 1024); k += 4096) {
      dE[k] = 0xFFFFFFFFu;
      S[k] = 0.f;
    }
    if (t == 0) out[0] = 0.f;
  }
}

// ---------------------------------------------------------------------------
// Layer-1 pass kernels: 32x32x16 MFMA. 4 waves/block, wave owns TI 32-wide
// i-tiles; fy j-tiles (32 wide, KC=C/16 chunks, 8 KB) shared via LDS,
// double-buffered (R6 structure). C/D: i = lane&31 (col), j = reg/lane>>5
// (row) -> per-i reduction = 16-reg fold + shfl_xor(32).
// ---------------------------------------------------------------------------
template <int HW, int C, int TI, int JSPLIT, int MINW>
__global__ __launch_bounds__(256, MINW) void passA32(
    const uint4* __restrict__ fxB, const uint4* __restrict__ fyB,
    unsigned* __restrict__ dminEnc) {
  constexpr int KC = C / 16;
  constexpr int JB = HW / 32;
  constexpr int IBW = 4 * TI;        // 32-wide i-tiles per block
  constexpr int JPS = JB / JSPLIT;
  constexpr int TILE = KC * 64;      // uint4 per 32-j tile
  __shared__ uint4 sbuf[2 * TILE];
  const int lane = threadIdx.x & 63, wv = threadIdx.x >> 6;
  const int sample = blockIdx.x & 7, rem = blockIdx.x >> 3;
  const int ib = (rem / JSPLIT) * IBW + wv * TI;
  const int jt0 = (rem % JSPLIT) * JPS;
  const uint4* fx = fxB + (size_t)sample * (HW / 32) * TILE;
  const uint4* fy = fyB + (size_t)sample * (HW / 32) * TILE;

  auto stage = [&](int jt, int buf) {
    const uint4* g = fy + (size_t)jt * TILE;
    uint4* l = sbuf + buf * TILE;
    for (int t = threadIdx.x; t < TILE; t += 256) dma16(g + t, l + t);
  };
  stage(jt0, 0);

  short8 bf[TI][KC];
#pragma unroll
  for (int ti = 0; ti < TI; ++ti)
#pragma unroll
    for (int kc = 0; kc < KC; ++kc) {
      uint4 t = fx[(size_t)((ib + ti) * KC + kc) * 64 + lane];
      bf[ti][kc] = *(short8*)&t;
    }

  float smax[TI];
#pragma unroll
  for (int ti = 0; ti < TI; ++ti) smax[ti] = -1e30f;

  for (int s = 0; s < JPS; ++s) {
    const int cur = s & 1;
    __syncthreads();
    if (s + 1 < JPS) stage(jt0 + s + 1, cur ^ 1);
    const uint4* sb = sbuf + cur * TILE;
    f32x16 acc[TI];
#pragma unroll
    for (int ti = 0; ti < TI; ++ti)
#pragma unroll
      for (int r = 0; r < 16; ++r) acc[ti][r] = 0.f;
#pragma unroll
    for (int kc = 0; kc < KC; ++kc) {
      uint4 t = sb[kc * 64 + lane];
      short8 a = *(short8*)&t;
#pragma unroll
      for (int ti = 0; ti < TI; ++ti)
        acc[ti] = __builtin_amdgcn_mfma_f32_32x32x16_bf16(a, bf[ti][kc], acc[ti], 0, 0, 0);
    }
#pragma unroll
    for (int ti = 0; ti < TI; ++ti)
#pragma unroll
      for (int r = 0; r < 16; ++r) smax[ti] = fmaxf(smax[ti], acc[ti][r]);
  }

#pragma unroll
  for (int ti = 0; ti < TI; ++ti) {
    float v = fmaxf(smax[ti], __shfl_xor(smax[ti], 32));
    if (lane < 32)
      atomicMin(&dminEnc[(size_t)sample * HW + (ib + ti) * 32 + lane],
                encf(1.0f - v));
  }
}

template <int HW, int C, int TI, int JSPLIT, int MINW>
__global__ __launch_bounds__(256, MINW) void passB32(
    const uint4* __restrict__ fxB, const uint4* __restrict__ fyB,
    const unsigned* __restrict__ dminEnc, float* __restrict__ Ssum) {
  constexpr int KC = C / 16;
  constexpr int JB = HW / 32;
  constexpr int IBW = 4 * TI;
  constexpr int JPS = JB / JSPLIT;
  constexpr int TILE = KC * 64;
  __shared__ uint4 sbuf[2 * TILE];
  const int lane = threadIdx.x & 63, wv = threadIdx.x >> 6, l31 = lane & 31;
  const int sample = blockIdx.x & 7, rem = blockIdx.x >> 3;
  const int ib = (rem / JSPLIT) * IBW + wv * TI;
  const int jt0 = (rem % JSPLIT) * JPS;
  const uint4* fx = fxB + (size_t)sample * (HW / 32) * TILE;
  const uint4* fy = fyB + (size_t)sample * (HW / 32) * TILE;

  auto stage = [&](int jt, int buf) {
    const uint4* g = fy + (size_t)jt * TILE;
    uint4* l = sbuf + buf * TILE;
    for (int t = threadIdx.x; t < TILE; t += 256) dma16(g + t, l + t);
  };
  stage(jt0, 0);

  short8 bf[TI][KC];
#pragma unroll
  for (int ti = 0; ti < TI; ++ti)
#pragma unroll
    for (int kc = 0; kc < KC; ++kc) {
      uint4 t = fx[(size_t)((ib + ti) * KC + kc) * 64 + lane];
      bf[ti][kc] = *(short8*)&t;
    }

  float c0v[TI], c1v[TI];
#pragma unroll
  for (int ti = 0; ti < TI; ++ti) {
    float dmin = decf(dminEnc[(size_t)sample * HW + (ib + ti) * 32 + l31]);
    float dinv = 1.0f / (dmin + EPS);
    c1v[ti] = dinv * KEXP;
    c0v[ti] = (1.0f - dinv) * KEXP;
  }

  float ssum[TI];
#pragma unroll
  for (int ti = 0; ti < TI; ++ti) ssum[ti] = 0.f;

  for (int s = 0; s < JPS; ++s) {
    const int cur = s & 1;
    __syncthreads();
    if (s + 1 < JPS) stage(jt0 + s + 1, cur ^ 1);
    const uint4* sb = sbuf + cur * TILE;
    f32x16 acc[TI];
#pragma unroll
    for (int ti = 0; ti < TI; ++ti)
#pragma unroll
      for (int r = 0; r < 16; ++r) acc[ti][r] = 0.f;
#pragma unroll
    for (int kc = 0; kc < KC; ++kc) {
      uint4 t = sb[kc * 64 + lane];
      short8 a = *(short8*)&t;
#pragma unroll
      for (int ti = 0; ti < TI; ++ti)
        acc[ti] = __builtin_amdgcn_mfma_f32_32x32x16_bf16(a, bf[ti][kc], acc[ti], 0, 0, 0);
    }
#pragma unroll
    for (int ti = 0; ti < TI; ++ti)
#pragma unroll
      for (int r = 0; r < 16; ++r)
        ssum[ti] += __builtin_amdgcn_exp2f(fmaf(acc[ti][r], c1v[ti], c0v[ti]));
  }

#pragma unroll
  for (int ti = 0; ti < TI; ++ti) {
    float v = ssum[ti] + __shfl_xor(ssum[ti], 32);
    if (lane < 32)
      atomicAdd(&Ssum[(size_t)sample * HW + (ib + ti) * 32 + lane], v);
  }
}

// ---------------------------------------------------------------------------
// Layer-2 pass kernels: proven R6 16x16x32 path, unchanged.
// ---------------------------------------------------------------------------
template <int HW, int C, int TI, int JSPLIT, int MINW>
__global__ __launch_bounds__(256, MINW) void passA16(
    const uint4* __restrict__ fxB, const uint4* __restrict__ fyB,
    unsigned* __restrict__ dminEnc) {
  constexpr int KC = C / 32;
  constexpr int JB = HW / 16;
  constexpr int IBW = 4 * TI;
  constexpr int JPS = JB / JSPLIT;
  constexpr int TILE = KC * 64;
  __shared__ uint4 sbuf[2 * TILE];
  const int lane = threadIdx.x & 63, wv = threadIdx.x >> 6, l15 = lane & 15;
  const int sample = blockIdx.x & 7, rem = blockIdx.x >> 3;
  const int ib = (rem / JSPLIT) * IBW + wv * TI;
  const int jt0 = (rem % JSPLIT) * JPS;
  const uint4* fx = fxB + (size_t)sample * JB * TILE;
  const uint4* fy = fyB + (size_t)sample * JB * TILE;

  auto stage = [&](int jt, int buf) {
    const uint4* g = fy + (size_t)jt * TILE;
    uint4* l = sbuf + buf * TILE;
    for (int t = threadIdx.x; t < TILE; t += 256) dma16(g + t, l + t);
  };
  stage(jt0, 0);

  short8 bf[TI][KC];
#pragma unroll
  for (int ti = 0; ti < TI; ++ti)
#pragma unroll
    for (int kc = 0; kc < KC; ++kc) {
      uint4 t = fx[(size_t)((ib + ti) * KC + kc) * 64 + lane];
      bf[ti][kc] = *(short8*)&t;
    }

  float smax[TI];
#pragma unroll
  for (int ti = 0; ti < TI; ++ti) smax[ti] = -1e30f;

  for (int s = 0; s < JPS; ++s) {
    const int cur = s & 1;
    __syncthreads();
    if (s + 1 < JPS) stage(jt0 + s + 1, cur ^ 1);
    const uint4* sb = sbuf + cur * TILE;
    f32x4 acc[TI];
#pragma unroll
    for (int ti = 0; ti < TI; ++ti)
#pragma unroll
      for (int r = 0; r < 4; ++r) acc[ti][r] = 0.f;
#pragma unroll
    for (int kc = 0; kc < KC; ++kc) {
      uint4 t = sb[kc * 64 + lane];
      short8 a = *(short8*)&t;
#pragma unroll
      for (int ti = 0; ti < TI; ++ti)
        acc[ti] = __builtin_amdgcn_mfma_f32_16x16x32_bf16(a, bf[ti][kc], acc[ti], 0, 0, 0);
    }
#pragma unroll
    for (int ti = 0; ti < TI; ++ti)
#pragma unroll
      for (int r = 0; r < 4; ++r) smax[ti] = fmaxf(smax[ti], acc[ti][r]);
  }

#pragma unroll
  for (int ti = 0; ti < TI; ++ti) {
    float v = smax[ti];
    v = fmaxf(v, __shfl_xor(v, 16));
    v = fmaxf(v, __shfl_xor(v, 32));
    if (lane < 16)
      atomicMin(&dminEnc[(size_t)sample * HW + (ib + ti) * 16 + l15],
                encf(1.0f - v));
  }
}

template <int HW, int C, int TI, int JSPLIT, int MINW>
__global__ __launch_bounds__(256, MINW) void passB16(
    const uint4* __restrict__ fxB, const uint4* __restrict__ fyB,
    const unsigned* __restrict__ dminEnc, float* __restrict__ Ssum) {
  constexpr int KC = C / 32;
  constexpr int JB = HW / 16;
  constexpr int IBW = 4 * TI;
  constexpr int JPS = JB / JSPLIT;
  constexpr int TILE = KC * 64;
  __shared__ uint4 sbuf[2 * TILE];
  const int lane = threadIdx.x & 63, wv = threadIdx.x >> 6, l15 = lane & 15;
  const int sample = blockIdx.x & 7, rem = blockIdx.x >> 3;
  const int ib = (rem / JSPLIT) * IBW + wv * TI;
  const int jt0 = (rem % JSPLIT) * JPS;
  const uint4* fx = fxB + (size_t)sample * JB * TILE;
  const uint4* fy = fyB + (size_t)sample * JB * TILE;

  auto stage = [&](int jt, int buf) {
    const uint4* g = fy + (size_t)jt * TILE;
    uint4* l = sbuf + buf * TILE;
    for (int t = threadIdx.x; t < TILE; t += 256) dma16(g + t, l + t);
  };
  stage(jt0, 0);

  short8 bf[TI][KC];
#pragma unroll
  for (int ti = 0; ti < TI; ++ti)
#pragma unroll
    for (int kc = 0; kc < KC; ++kc) {
      uint4 t = fx[(size_t)((ib + ti) * KC + kc) * 64 + lane];
      bf[ti][kc] = *(short8*)&t;
    }

  float c0v[TI], c1v[TI];
#pragma unroll
  for (int ti = 0; ti < TI; ++ti) {
    float dmin = decf(dminEnc[(size_t)sample * HW + (ib + ti) * 16 + l15]);
    float dinv = 1.0f / (dmin + EPS);
    c1v[ti] = dinv * KEXP;
    c0v[ti] = (1.0f - dinv) * KEXP;
  }

  float ssum[TI];
#pragma unroll
  for (int ti = 0; ti < TI; ++ti) ssum[ti] = 0.f;

  for (int s = 0; s < JPS; ++s) {
    const int cur = s & 1;
    __syncthreads();
    if (s + 1 < JPS) stage(jt0 + s + 1, cur ^ 1);
    const uint4* sb = sbuf + cur * TILE;
    f32x4 acc[TI];
#pragma unroll
    for (int ti = 0; ti < TI; ++ti)
#pragma unroll
      for (int r = 0; r < 4; ++r) acc[ti][r] = 0.f;
#pragma unroll
    for (int kc = 0; kc < KC; ++kc) {
      uint4 t = sb[kc * 64 + lane];
      short8 a = *(short8*)&t;
#pragma unroll
      for (int ti = 0; ti < TI; ++ti)
        acc[ti] = __builtin_amdgcn_mfma_f32_16x16x32_bf16(a, bf[ti][kc], acc[ti], 0, 0, 0);
    }
#pragma unroll
    for (int ti = 0; ti < TI; ++ti)
#pragma unroll
      for (int r = 0; r < 4; ++r)
        ssum[ti] += __builtin_amdgcn_exp2f(fmaf(acc[ti][r], c1v[ti], c0v[ti]));
  }

#pragma unroll
  for (int ti = 0; ti < TI; ++ti) {
    float v = ssum[ti];
    v += __shfl_xor(v, 16);
    v += __shfl_xor(v, 32);
    if (lane < 16)
      atomicAdd(&Ssum[(size_t)sample * HW + (ib + ti) * 16 + l15], v);
  }
}

// ---------------------------------------------------------------------------
// reduce_out: one block per sample; atomicAdd(-log(cx+EPS)/16) into out[0].
// ---------------------------------------------------------------------------
__global__ __launch_bounds__(256) void reduce_out(
    const unsigned* __restrict__ dE1, const float* __restrict__ S1,
    const unsigned* __restrict__ dE2, const float* __restrict__ S2,
    float* __restrict__ out) {
  const int s = blockIdx.x;
  const unsigned* dE;
  const float* Sp;
  int HW;
  if (s < 8) { dE = dE1 + (size_t)s * 4096; Sp = S1 + (size_t)s * 4096; HW = 4096; }
  else       { dE = dE2 + (size_t)(s - 8) * 1024; Sp = S2 + (size_t)(s - 8) * 1024; HW = 1024; }
  float t = 0.f;
  for (int i = threadIdx.x; i < HW; i += 256) {
    float dmin = decf(dE[i]);
    float dinv = 1.0f / (dmin + EPS);
    float wmx = __builtin_amdgcn_exp2f((1.0f - dmin * dinv) * KEXP);
    t += wmx / (Sp[i] + EPS);
  }
  __shared__ float red[4];
  t += __shfl_xor(t, 1);  t += __shfl_xor(t, 2);  t += __shfl_xor(t, 4);
  t += __shfl_xor(t, 8);  t += __shfl_xor(t, 16); t += __shfl_xor(t, 32);
  if ((threadIdx.x & 63) == 0) red[threadIdx.x >> 6] = t;
  __syncthreads();
  if (threadIdx.x == 0) {
    float cx = (red[0] + red[1] + red[2] + red[3]) / (float)HW;
    atomicAdd(out, -logf(cx + EPS) * (1.0f / 16.0f));
  }
}

extern "C" void kernel_launch(void* const* d_in, const int* in_sizes, int n_in,
                              void* d_out, int out_size, void* d_ws, size_t ws_size,
                              hipStream_t stream) {
  const float* fx1 = (const float*)d_in[0];  // (8,128,64,64)
  const float* fy1 = (const float*)d_in[1];
  const float* fx2 = (const float*)d_in[2];  // (8,256,32,32)
  const float* fy2 = (const float*)d_in[3];
  float* out = (float*)d_out;

  const int B = 8, HW1 = 4096, HW2 = 1024;

  char* w = (char*)d_ws;
  unsigned* dE1 = (unsigned*)w;                      // 8*4096 u32
  unsigned* dE2 = dE1 + (size_t)B * HW1;             // 8*1024 u32
  float*    S1  = (float*)(dE2 + (size_t)B * HW2);   // 8*4096 f
  float*    S2  = S1 + (size_t)B * HW1;              // 8*1024 f
  uint4*    fx1B = (uint4*)((char*)(S2 + (size_t)B * HW2) + 1024);
  const size_t n1 = (size_t)B * (HW1 / 32) * (128 / 16) * 64;  // 8 MB (32-blocked)
  const size_t n2 = (size_t)B * (HW2 / 16) * (256 / 32) * 64;  // 4 MB (16-blocked)
  uint4* fy1B = fx1B + n1;
  uint4* fx2B = fy1B + n1;
  uint4* fy2B = fx2B + n2;   // total ~24.4 MB

  prep_all<<<336, 256, 0, stream>>>(fx1, fx1B, fy1, fy1B, fx2, fx2B, fy2, fy2B,
                                    dE1, S1, out);

  // layer1 (32x32x16): TI=2 -> wave i-width 64, block 256; IPB=16; JSPLIT=8
  //   -> 8*16*8 = 1024 blocks of 256 thr; LDS 16 KB; MINW=4 (4 blocks/CU)
  // layer2 (16x16x32): R6 config TI=2, JSPLIT=8 -> 512 blocks; MINW=4
  passA32<4096, 128, 2, 8, 4><<<1024, 256, 0, stream>>>(fx1B, fy1B, dE1);
  passA16<1024, 256, 2, 8, 4><<<512, 256, 0, stream>>>(fx2B, fy2B, dE2);
  passB32<4096, 128, 2, 8, 4><<<1024, 256, 0, stream>>>(fx1B, fy1B, dE1, S1);
  passB16<1024, 256, 2, 8, 4><<<512, 256, 0, stream>>>(fx2B, fy2B, dE2, S2);

  reduce_out<<<16, 256, 0, stream>>>(dE1, S1, dE2, S2, out);
}